// Round 1
// baseline (2733.492 us; speedup 1.0000x reference)
//
#include <hip/hip_runtime.h>
#include <math.h>

#define BB 8
#define TT 2048
#define CC 768
#define MM (BB*TT)

// ================= QKV projection: Y[m,n] = sum_k X[m,k]*W[n,k] =================
#define PBM 128
#define PBN 128
#define PBK 32

__global__ __launch_bounds__(256) void qkv_gemm_f32(
    const float* __restrict__ X,
    const float* __restrict__ W0, const float* __restrict__ W1, const float* __restrict__ W2,
    float* __restrict__ Y0, float* __restrict__ Y1, float* __restrict__ Y2)
{
    __shared__ float Xs[PBK][PBM];
    __shared__ float Ws[PBK][PBN];
    const int tid = threadIdx.x;
    const int m0 = blockIdx.y * PBM;
    const int n0 = blockIdx.x * PBN;
    const float* __restrict__ W = (blockIdx.z == 0) ? W0 : (blockIdx.z == 1) ? W1 : W2;
    float* __restrict__ Y       = (blockIdx.z == 0) ? Y0 : (blockIdx.z == 1) ? Y1 : Y2;

    const int ty = tid >> 4, tx = tid & 15;

    float acc[8][8];
#pragma unroll
    for (int i = 0; i < 8; ++i)
#pragma unroll
        for (int j = 0; j < 8; ++j) acc[i][j] = 0.f;

    float4 xr[4], wr[4];
    // prologue: load k-tile 0 into registers
#pragma unroll
    for (int i = 0; i < 4; ++i) {
        int id = tid + i*256;
        int row = id >> 3, c4 = id & 7;           // 128 rows x 8 float4
        xr[i] = *(const float4*)(X + (size_t)(m0+row)*CC + c4*4);
        wr[i] = *(const float4*)(W + (size_t)(n0+row)*CC + c4*4);
    }
    for (int k0 = 0; k0 < CC; k0 += PBK) {
        __syncthreads();   // previous compute done with LDS
#pragma unroll
        for (int i = 0; i < 4; ++i) {
            int id = tid + i*256;
            int row = id >> 3, c4 = id & 7;
            Xs[c4*4+0][row]=xr[i].x; Xs[c4*4+1][row]=xr[i].y; Xs[c4*4+2][row]=xr[i].z; Xs[c4*4+3][row]=xr[i].w;
            Ws[c4*4+0][row]=wr[i].x; Ws[c4*4+1][row]=wr[i].y; Ws[c4*4+2][row]=wr[i].z; Ws[c4*4+3][row]=wr[i].w;
        }
        __syncthreads();   // LDS tile ready
        if (k0 + PBK < CC) {   // prefetch next k-tile into registers (hides under compute)
#pragma unroll
            for (int i = 0; i < 4; ++i) {
                int id = tid + i*256;
                int row = id >> 3, c4 = id & 7;
                xr[i] = *(const float4*)(X + (size_t)(m0+row)*CC + (k0+PBK) + c4*4);
                wr[i] = *(const float4*)(W + (size_t)(n0+row)*CC + (k0+PBK) + c4*4);
            }
        }
#pragma unroll
        for (int k = 0; k < PBK; ++k) {
            float a[8], b[8];
            *(float4*)&a[0] = *(const float4*)&Xs[k][ty*4];
            *(float4*)&a[4] = *(const float4*)&Xs[k][64 + ty*4];
            *(float4*)&b[0] = *(const float4*)&Ws[k][tx*4];
            *(float4*)&b[4] = *(const float4*)&Ws[k][64 + tx*4];
#pragma unroll
            for (int i = 0; i < 8; ++i)
#pragma unroll
                for (int j = 0; j < 8; ++j)
                    acc[i][j] = fmaf(a[i], b[j], acc[i][j]);
        }
    }
    // store 8x8 per thread (rows ty*4.. and 64+ty*4.., cols tx*4.. and 64+tx*4..)
#pragma unroll
    for (int i = 0; i < 8; ++i) {
        int row = (i < 4) ? (ty*4 + i) : (64 + ty*4 + (i - 4));
        float4 v0 = make_float4(acc[i][0], acc[i][1], acc[i][2], acc[i][3]);
        float4 v1 = make_float4(acc[i][4], acc[i][5], acc[i][6], acc[i][7]);
        *(float4*)(Y + (size_t)(m0+row)*CC + n0 + tx*4)      = v0;
        *(float4*)(Y + (size_t)(m0+row)*CC + n0 + 64 + tx*4) = v1;
    }
}

// ================= causal flash attention, fp32 =================
// Block: 512 threads. Q-tile 32 rows resident in LDS; K/V streamed in 64x128 chunks.
// Thread role: q = tid>>4 (0..31 query row), l16 = tid&15 (S col-band / output d-band).
#define QT 32
#define KT 64
#define KC 128
#define NQT (TT/QT)                 // 64 q-tiles
#define SOFT_SCALE 0.03608439182435161f   // 1/sqrt(768)

__global__ __launch_bounds__(512) void attn_f32(
    const float* __restrict__ Qg, const float* __restrict__ Kg, const float* __restrict__ Vg,
    float* __restrict__ Og)
{
    __shared__ float Qs[QT][CC + 4];     // 98816 B, +4 pad -> conflict-free b128 reads
    __shared__ float KVs[KT][KC + 4];    // 33792 B, shared by K-chunks and V-chunks
    __shared__ float Ps[QT][KT + 1];     //  8320 B

    const int tid = threadIdx.x;
    const int b = blockIdx.y;
    const size_t bT = (size_t)b * TT;
    const int q = tid >> 4;
    const int l16 = tid & 15;

    float4 ldreg[4];   // register staging for global->LDS (issue-early / write-late)

    for (int half = 0; half < 2; ++half) {
        // pair q-tiles (i, 63-i): every block processes exactly 33 key tiles total
        const int qt = half ? (NQT - 1 - blockIdx.x) : blockIdx.x;
        const int qglob = qt * QT + q;
        const int nkt = qt / 2 + 1;

        __syncthreads();   // protect Qs overwrite across halves
#pragma unroll
        for (int i = 0; i < 12; ++i) {    // 32 rows x 192 float4
            int id = tid + i*512;
            int row = id / 192, c4 = id % 192;
            *(float4*)&Qs[row][c4*4] = *(const float4*)(Qg + (bT + qt*QT + row)*CC + c4*4);
        }

        float out_acc[6][8];
#pragma unroll
        for (int i = 0; i < 6; ++i)
#pragma unroll
            for (int j = 0; j < 8; ++j) out_acc[i][j] = 0.f;
        float mrun = -1e30f, lrun = 0.f;

        for (int kt = 0; kt < nkt; ++kt) {
            const int s0 = kt * KT;
            // -------- S = Q K^T (chunked over k, 6 chunks of 128) --------
            float sacc[4] = {0.f, 0.f, 0.f, 0.f};
#pragma unroll
            for (int i = 0; i < 4; ++i) {   // prologue: K chunk 0 -> regs
                int id = tid + i*512;
                int r = id >> 5, cc = id & 31;
                ldreg[i] = *(const float4*)(Kg + (bT + s0 + r)*CC + cc*4);
            }
            for (int kc = 0; kc < CC/KC; ++kc) {
                __syncthreads();                       // LDS chunk free
#pragma unroll
                for (int i = 0; i < 4; ++i) {
                    int id = tid + i*512;
                    int r = id >> 5, cc = id & 31;
                    *(float4*)&KVs[r][cc*4] = ldreg[i];
                }
                __syncthreads();                       // chunk ready
                const float* nsrc = (kc + 1 < CC/KC) ? Kg : Vg;   // last K chunk prefetches V chunk 0
                const int ncol    = (kc + 1 < CC/KC) ? (kc + 1)*KC : 0;
#pragma unroll
                for (int i = 0; i < 4; ++i) {
                    int id = tid + i*512;
                    int r = id >> 5, cc = id & 31;
                    ldreg[i] = *(const float4*)(nsrc + (bT + s0 + r)*CC + ncol + cc*4);
                }
#pragma unroll 4
                for (int k4 = 0; k4 < KC/4; ++k4) {
                    float4 qv = *(const float4*)&Qs[q][kc*KC + k4*4];
#pragma unroll
                    for (int jj = 0; jj < 4; ++jj) {
                        float4 kv = *(const float4*)&KVs[jj*16 + l16][k4*4];
                        sacc[jj] = fmaf(qv.x, kv.x, sacc[jj]);
                        sacc[jj] = fmaf(qv.y, kv.y, sacc[jj]);
                        sacc[jj] = fmaf(qv.z, kv.z, sacc[jj]);
                        sacc[jj] = fmaf(qv.w, kv.w, sacc[jj]);
                    }
                }
            }
            // -------- online softmax (in-wave, 16-lane row groups) --------
            float mt = -1e30f;
#pragma unroll
            for (int jj = 0; jj < 4; ++jj) {
                int key = s0 + jj*16 + l16;
                float sv = sacc[jj] * SOFT_SCALE;
                sv = (key > qglob) ? -1e30f : sv;      // causal mask
                sacc[jj] = sv;
                mt = fmaxf(mt, sv);
            }
#pragma unroll
            for (int off = 1; off < 16; off <<= 1) mt = fmaxf(mt, __shfl_xor(mt, off));
            float mnew = fmaxf(mrun, mt);
            float corr = __expf(mrun - mnew);
            float rs = 0.f;
#pragma unroll
            for (int jj = 0; jj < 4; ++jj) {
                float p = __expf(sacc[jj] - mnew);
                Ps[q][jj*16 + l16] = p;
                rs += p;
            }
#pragma unroll
            for (int off = 1; off < 16; off <<= 1) rs += __shfl_xor(rs, off);
            lrun = lrun * corr + rs;
            mrun = mnew;
#pragma unroll
            for (int i = 0; i < 6; ++i)
#pragma unroll
                for (int j = 0; j < 8; ++j) out_acc[i][j] *= corr;

            // -------- out += P @ V (V chunk 0 already staged in ldreg) --------
#pragma unroll
            for (int dc = 0; dc < 6; ++dc) {
                __syncthreads();
#pragma unroll
                for (int i = 0; i < 4; ++i) {
                    int id = tid + i*512;
                    int r = id >> 5, cc = id & 31;
                    *(float4*)&KVs[r][cc*4] = ldreg[i];
                }
                __syncthreads();
                if (dc + 1 < 6) {
#pragma unroll
                    for (int i = 0; i < 4; ++i) {
                        int id = tid + i*512;
                        int r = id >> 5, cc = id & 31;
                        ldreg[i] = *(const float4*)(Vg + (bT + s0 + r)*CC + (dc+1)*KC + cc*4);
                    }
                }
#pragma unroll 2
                for (int s = 0; s < KT; ++s) {
                    float pw = Ps[q][s];
                    float4 v0 = *(const float4*)&KVs[s][l16*4];
                    float4 v1 = *(const float4*)&KVs[s][64 + l16*4];
                    out_acc[dc][0] = fmaf(pw, v0.x, out_acc[dc][0]);
                    out_acc[dc][1] = fmaf(pw, v0.y, out_acc[dc][1]);
                    out_acc[dc][2] = fmaf(pw, v0.z, out_acc[dc][2]);
                    out_acc[dc][3] = fmaf(pw, v0.w, out_acc[dc][3]);
                    out_acc[dc][4] = fmaf(pw, v1.x, out_acc[dc][4]);
                    out_acc[dc][5] = fmaf(pw, v1.y, out_acc[dc][5]);
                    out_acc[dc][6] = fmaf(pw, v1.z, out_acc[dc][6]);
                    out_acc[dc][7] = fmaf(pw, v1.w, out_acc[dc][7]);
                }
            }
        }
        // -------- epilogue --------
        float inv = 1.0f / lrun;
#pragma unroll
        for (int dc = 0; dc < 6; ++dc) {
            float4 o0 = make_float4(out_acc[dc][0]*inv, out_acc[dc][1]*inv, out_acc[dc][2]*inv, out_acc[dc][3]*inv);
            float4 o1 = make_float4(out_acc[dc][4]*inv, out_acc[dc][5]*inv, out_acc[dc][6]*inv, out_acc[dc][7]*inv);
            *(float4*)(Og + (bT + qglob)*CC + dc*KC + l16*4)      = o0;
            *(float4*)(Og + (bT + qglob)*CC + dc*KC + 64 + l16*4) = o1;
        }
    }
}

extern "C" void kernel_launch(void* const* d_in, const int* in_sizes, int n_in,
                              void* d_out, int out_size, void* d_ws, size_t ws_size,
                              hipStream_t stream) {
    const float* x  = (const float*)d_in[0];
    const float* Wq = (const float*)d_in[1];
    const float* Wk = (const float*)d_in[2];
    const float* Wv = (const float*)d_in[3];
    float* out = (float*)d_out;

    float* Q = (float*)d_ws;                  // 3 x 16384 x 768 fp32 = 151 MB scratch
    float* K = Q + (size_t)MM * CC;
    float* V = K + (size_t)MM * CC;

    qkv_gemm_f32<<<dim3(CC/PBN, MM/PBM, 3), 256, 0, stream>>>(x, Wq, Wk, Wv, Q, K, V);
    attn_f32<<<dim3(NQT/2, BB), 512, 0, stream>>>(Q, K, V, out);
}

// Round 5
// 473.295 us; speedup vs baseline: 5.7755x; 5.7755x over previous
//
#include <hip/hip_runtime.h>
#include <math.h>

#define MM 16384
#define TT 2048
#define BB 8
#define CC 768
#define SOFT_SCALE 0.03608439182435161f   // 1/sqrt(768)

typedef _Float16 f16;
typedef _Float16 half8 __attribute__((ext_vector_type(8)));
typedef _Float16 half4 __attribute__((ext_vector_type(4)));
typedef float f32x4 __attribute__((ext_vector_type(4)));

// Swizzled LDS tile addressing: [128 rows][64 f16], row pitch 128 B.
// XOR byte bits 4-6 with row&7 -> conflict-free ds_read_b128 (T2).
__device__ __forceinline__ int swz(int r, int cbyte) {
    return r * 128 + (cbyte ^ ((r & 7) << 4));
}

// ---------------------------------------------------------------------------
// Kernel 1: QKV projection.  Y[m,n] = sum_k X[m,k] * W[n,k]  (fp32 in, f16 out)
// z=0 -> Q (row-major), z=1 -> K (row-major), z=2 -> V stored TRANSPOSED per
// batch: Vt[b][d][t].
// ---------------------------------------------------------------------------
__global__ __launch_bounds__(256) void qkv_gemm(
    const float* __restrict__ X, const float* __restrict__ W0,
    const float* __restrict__ W1, const float* __restrict__ W2,
    f16* __restrict__ Qh, f16* __restrict__ Kh, f16* __restrict__ Vt)
{
    __shared__ char SM[34 * 1024];
    f16* As = (f16*)SM;               // [128][64] swizzled
    f16* Bs = (f16*)(SM + 16 * 1024);

    const int tid = threadIdx.x;
    const int z = blockIdx.z;
    const float* __restrict__ Wm = (z == 0) ? W0 : (z == 1) ? W1 : W2;
    const int n0 = blockIdx.x * 128;
    const int m0 = blockIdx.y * 128;

    const int lane = tid & 63;
    const int w = tid >> 6;
    const int wr = w >> 1, wc = w & 1;
    const int l15 = lane & 15, lk = lane >> 4;

    f32x4 acc[4][4];
#pragma unroll
    for (int i = 0; i < 4; ++i)
#pragma unroll
        for (int j = 0; j < 4; ++j) acc[i][j] = (f32x4){0.f, 0.f, 0.f, 0.f};

    const int srow = tid >> 1;          // 0..127
    const int scol = (tid & 1) * 32;    // element col base within BK=64

    const float* ga = X  + (size_t)(m0 + srow) * CC + scol;
    const float* gb = Wm + (size_t)(n0 + srow) * CC + scol;

    float4 ra[8], rb[8];
#pragma unroll
    for (int i = 0; i < 8; ++i) {
        ra[i] = *(const float4*)(ga + i * 4);
        rb[i] = *(const float4*)(gb + i * 4);
    }

    for (int k0 = 0; k0 < CC; k0 += 64) {
        __syncthreads();
#pragma unroll
        for (int c = 0; c < 4; ++c) {            // 4 chunks of 8 halves
            half8 ha, hb;
            const float* fa = (const float*)&ra[2 * c];
            const float* fb = (const float*)&rb[2 * c];
#pragma unroll
            for (int j = 0; j < 8; ++j) { ha[j] = (f16)fa[j]; hb[j] = (f16)fb[j]; }
            *(half8*)((char*)As + swz(srow, (scol + c * 8) * 2)) = ha;
            *(half8*)((char*)Bs + swz(srow, (scol + c * 8) * 2)) = hb;
        }
        __syncthreads();
        if (k0 + 64 < CC) {
#pragma unroll
            for (int i = 0; i < 8; ++i) {
                ra[i] = *(const float4*)(ga + (k0 + 64) + i * 4);
                rb[i] = *(const float4*)(gb + (k0 + 64) + i * 4);
            }
        }
#pragma unroll
        for (int kk = 0; kk < 2; ++kk) {
            half8 a[4], b[4];
#pragma unroll
            for (int i = 0; i < 4; ++i)
                a[i] = *(const half8*)((char*)As + swz(wr * 64 + i * 16 + l15, (kk * 32 + lk * 8) * 2));
#pragma unroll
            for (int j = 0; j < 4; ++j)
                b[j] = *(const half8*)((char*)Bs + swz(wc * 64 + j * 16 + l15, (kk * 32 + lk * 8) * 2));
#pragma unroll
            for (int i = 0; i < 4; ++i)
#pragma unroll
                for (int j = 0; j < 4; ++j)
                    acc[i][j] = __builtin_amdgcn_mfma_f32_16x16x32_f16(a[i], b[j], acc[i][j], 0, 0, 0);
        }
    }

    if (z < 2) {
        f16* __restrict__ Y = (z == 0) ? Qh : Kh;
#pragma unroll
        for (int i = 0; i < 4; ++i)
#pragma unroll
            for (int r = 0; r < 4; ++r) {
                int m = m0 + wr * 64 + i * 16 + lk * 4 + r;
#pragma unroll
                for (int j = 0; j < 4; ++j) {
                    int n = n0 + wc * 64 + j * 16 + l15;
                    Y[(size_t)m * CC + n] = (f16)acc[i][j][r];
                }
            }
    } else {
        // transpose via LDS bounce: bounce[n][m], pitch 136 f16 (272 B -> every
        // row 16B-aligned so the half8 copy-out loads are legal ds_read_b128).
        __syncthreads();
        f16* Bn = (f16*)SM;
#pragma unroll
        for (int i = 0; i < 4; ++i)
#pragma unroll
            for (int j = 0; j < 4; ++j) {
                int n = wc * 64 + j * 16 + l15;
                int m = wr * 64 + i * 16 + lk * 4;
                half4 v;
#pragma unroll
                for (int r = 0; r < 4; ++r) v[r] = (f16)acc[i][j][r];
                *(half4*)&Bn[n * 136 + m] = v;
            }
        __syncthreads();
        const int b  = m0 >> 11;          // 2048 tokens per batch
        const int t0 = m0 & 2047;
        const int nrow = tid >> 1, mc = (tid & 1) * 64;
        f16* dst = Vt + (size_t)b * CC * TT + (size_t)(n0 + nrow) * TT + t0 + mc;
        const f16* src = &Bn[nrow * 136 + mc];
#pragma unroll
        for (int c = 0; c < 8; ++c) *(half8*)(dst + c * 8) = *(const half8*)(src + c * 8);
    }
}

// ---------------------------------------------------------------------------
// Kernel 2: S[b][t][s] = (Q[t,:] . K[s,:]) * scale, causal lower tiles only.
// ---------------------------------------------------------------------------
__global__ __launch_bounds__(256) void qk_gemm(
    const f16* __restrict__ Qh, const f16* __restrict__ Kh, f16* __restrict__ S)
{
    const int tj = blockIdx.x, ti = blockIdx.y, b = blockIdx.z;
    if (tj > ti) return;

    __shared__ char SM[32 * 1024];
    f16* As = (f16*)SM;
    f16* Bs = (f16*)(SM + 16 * 1024);

    const int tid = threadIdx.x;
    const int m0 = ti * 128, n0 = tj * 128;
    const int lane = tid & 63;
    const int w = tid >> 6;
    const int wr = w >> 1, wc = w & 1;
    const int l15 = lane & 15, lk = lane >> 4;

    f32x4 acc[4][4];
#pragma unroll
    for (int i = 0; i < 4; ++i)
#pragma unroll
        for (int j = 0; j < 4; ++j) acc[i][j] = (f32x4){0.f, 0.f, 0.f, 0.f};

    const int srow = tid >> 1;
    const int scol = (tid & 1) * 32;

    const f16* ga = Qh + (size_t)b * TT * CC + (size_t)(m0 + srow) * CC + scol;
    const f16* gb = Kh + (size_t)b * TT * CC + (size_t)(n0 + srow) * CC + scol;

    half8 ra[4], rb[4];
#pragma unroll
    for (int i = 0; i < 4; ++i) {
        ra[i] = *(const half8*)(ga + i * 8);
        rb[i] = *(const half8*)(gb + i * 8);
    }

    for (int k0 = 0; k0 < CC; k0 += 64) {
        __syncthreads();
#pragma unroll
        for (int c = 0; c < 4; ++c) {
            *(half8*)((char*)As + swz(srow, (scol + c * 8) * 2)) = ra[c];
            *(half8*)((char*)Bs + swz(srow, (scol + c * 8) * 2)) = rb[c];
        }
        __syncthreads();
        if (k0 + 64 < CC) {
#pragma unroll
            for (int i = 0; i < 4; ++i) {
                ra[i] = *(const half8*)(ga + (k0 + 64) + i * 8);
                rb[i] = *(const half8*)(gb + (k0 + 64) + i * 8);
            }
        }
#pragma unroll
        for (int kk = 0; kk < 2; ++kk) {
            half8 a[4], bfr[4];
#pragma unroll
            for (int i = 0; i < 4; ++i)
                a[i] = *(const half8*)((char*)As + swz(wr * 64 + i * 16 + l15, (kk * 32 + lk * 8) * 2));
#pragma unroll
            for (int j = 0; j < 4; ++j)
                bfr[j] = *(const half8*)((char*)Bs + swz(wc * 64 + j * 16 + l15, (kk * 32 + lk * 8) * 2));
#pragma unroll
            for (int i = 0; i < 4; ++i)
#pragma unroll
                for (int j = 0; j < 4; ++j)
                    acc[i][j] = __builtin_amdgcn_mfma_f32_16x16x32_f16(a[i], bfr[j], acc[i][j], 0, 0, 0);
        }
    }

    f16* Sb = S + (size_t)b * TT * TT;
#pragma unroll
    for (int i = 0; i < 4; ++i)
#pragma unroll
        for (int r = 0; r < 4; ++r) {
            int t = m0 + wr * 64 + i * 16 + lk * 4 + r;
#pragma unroll
            for (int j = 0; j < 4; ++j) {
                int s = n0 + wc * 64 + j * 16 + l15;
                Sb[(size_t)t * TT + s] = (f16)(acc[i][j][r] * SOFT_SCALE);
            }
        }
}

// ---------------------------------------------------------------------------
// Kernel 3: row softmax, in place (S -> P = exp(s-m)), stores 1/l.
// Wave per row; rows paired (t, 2047-t) for load balance. Zero-pads each row
// to its 128-tile boundary so pv_gemm never reads poison.
// ---------------------------------------------------------------------------
__global__ __launch_bounds__(256) void softmax_ker(
    f16* __restrict__ S, float* __restrict__ linv)
{
    const int w = threadIdx.x >> 6, lane = threadIdx.x & 63;
    const int pidx = blockIdx.x * 4 + w;       // 0..8191
    const int b = pidx >> 10, q = pidx & 1023;
    f16* Sb = S + (size_t)b * TT * TT;

#pragma unroll
    for (int hh = 0; hh < 2; ++hh) {
        const int t = hh ? (TT - 1 - q) : q;
        f16* row = Sb + (size_t)t * TT;
        const int L = t + 1;

        float m = -1e30f;
        for (int s = lane * 8; s < L; s += 512) {
            half8 v = *(const half8*)(row + s);
#pragma unroll
            for (int j = 0; j < 8; ++j) {
                float f = (float)v[j];
                m = (s + j < L) ? fmaxf(m, f) : m;
            }
        }
#pragma unroll
        for (int o = 32; o >= 1; o >>= 1) m = fmaxf(m, __shfl_xor(m, o));

        float sum = 0.f;
        for (int s = lane * 8; s < L; s += 512) {
            half8 v = *(const half8*)(row + s);
            half8 p;
#pragma unroll
            for (int j = 0; j < 8; ++j) {
                float e = (s + j < L) ? __expf((float)v[j] - m) : 0.f;
                sum += e;
                p[j] = (f16)e;
            }
            *(half8*)(row + s) = p;
        }
#pragma unroll
        for (int o = 32; o >= 1; o >>= 1) sum += __shfl_xor(sum, o);
        if (lane == 0) linv[b * TT + t] = 1.0f / sum;

        const int pe = ((t >> 7) + 1) << 7;     // pad to tile boundary
        for (int s = L + lane; s < pe; s += 64) row[s] = (f16)0.f;
    }
}

// ---------------------------------------------------------------------------
// Kernel 4: O[b][t][d] = (1/l) * sum_s P[t][s] * Vt[d][s], causal K-extent.
// ---------------------------------------------------------------------------
__global__ __launch_bounds__(256) void pv_gemm(
    const f16* __restrict__ P, const f16* __restrict__ Vt,
    const float* __restrict__ linv, float* __restrict__ O)
{
    const int dj = blockIdx.x;
    const int ti = 15 - blockIdx.y;            // longest tiles dispatched first
    const int b = blockIdx.z;

    __shared__ char SM[32 * 1024];
    f16* As = (f16*)SM;
    f16* Bs = (f16*)(SM + 16 * 1024);

    const int tid = threadIdx.x;
    const int m0 = ti * 128, n0 = dj * 128;
    const int lane = tid & 63;
    const int w = tid >> 6;
    const int wr = w >> 1, wc = w & 1;
    const int l15 = lane & 15, lk = lane >> 4;

    f32x4 acc[4][4];
#pragma unroll
    for (int i = 0; i < 4; ++i)
#pragma unroll
        for (int j = 0; j < 4; ++j) acc[i][j] = (f32x4){0.f, 0.f, 0.f, 0.f};

    const int srow = tid >> 1;
    const int scol = (tid & 1) * 32;
    const int KE = (ti + 1) * 128;

    const f16* ga = P  + (size_t)b * TT * TT + (size_t)(m0 + srow) * TT + scol;
    const f16* gb = Vt + (size_t)b * CC * TT + (size_t)(n0 + srow) * TT + scol;

    half8 ra[4], rb[4];
#pragma unroll
    for (int i = 0; i < 4; ++i) {
        ra[i] = *(const half8*)(ga + i * 8);
        rb[i] = *(const half8*)(gb + i * 8);
    }

    for (int k0 = 0; k0 < KE; k0 += 64) {
        __syncthreads();
#pragma unroll
        for (int c = 0; c < 4; ++c) {
            *(half8*)((char*)As + swz(srow, (scol + c * 8) * 2)) = ra[c];
            *(half8*)((char*)Bs + swz(srow, (scol + c * 8) * 2)) = rb[c];
        }
        __syncthreads();
        if (k0 + 64 < KE) {
#pragma unroll
            for (int i = 0; i < 4; ++i) {
                ra[i] = *(const half8*)(ga + (k0 + 64) + i * 8);
                rb[i] = *(const half8*)(gb + (k0 + 64) + i * 8);
            }
        }
#pragma unroll
        for (int kk = 0; kk < 2; ++kk) {
            half8 a[4], bfr[4];
#pragma unroll
            for (int i = 0; i < 4; ++i)
                a[i] = *(const half8*)((char*)As + swz(wr * 64 + i * 16 + l15, (kk * 32 + lk * 8) * 2));
#pragma unroll
            for (int j = 0; j < 4; ++j)
                bfr[j] = *(const half8*)((char*)Bs + swz(wc * 64 + j * 16 + l15, (kk * 32 + lk * 8) * 2));
#pragma unroll
            for (int i = 0; i < 4; ++i)
#pragma unroll
                for (int j = 0; j < 4; ++j)
                    acc[i][j] = __builtin_amdgcn_mfma_f32_16x16x32_f16(a[i], bfr[j], acc[i][j], 0, 0, 0);
        }
    }

    float* Ob = O + (size_t)b * TT * CC;
#pragma unroll
    for (int i = 0; i < 4; ++i)
#pragma unroll
        for (int r = 0; r < 4; ++r) {
            int t = m0 + wr * 64 + i * 16 + lk * 4 + r;
            float sc = linv[b * TT + t];
#pragma unroll
            for (int j = 0; j < 4; ++j) {
                int d = n0 + wc * 64 + j * 16 + l15;
                Ob[(size_t)t * CC + d] = acc[i][j][r] * sc;
            }
        }
}

// ---------------------------------------------------------------------------
extern "C" void kernel_launch(void* const* d_in, const int* in_sizes, int n_in,
                              void* d_out, int out_size, void* d_ws, size_t ws_size,
                              hipStream_t stream) {
    (void)in_sizes; (void)n_in; (void)out_size; (void)ws_size;
    const float* x  = (const float*)d_in[0];
    const float* Wq = (const float*)d_in[1];
    const float* Wk = (const float*)d_in[2];
    const float* Wv = (const float*)d_in[3];

    f16* Qh = (f16*)d_ws;                            // 25.2 MB
    f16* Kh = Qh + (size_t)MM * CC;                  // 25.2 MB
    f16* Vt = Kh + (size_t)MM * CC;                  // 25.2 MB (transposed V)
    f16* S  = Vt + (size_t)MM * CC;                  // 67 MB  (S, then P in place)
    float* linv = (float*)(S + (size_t)BB * TT * TT);// 64 KB
    float* out = (float*)d_out;

    qkv_gemm   <<<dim3(6, 128, 3), 256, 0, stream>>>(x, Wq, Wk, Wv, Qh, Kh, Vt);
    qk_gemm    <<<dim3(16, 16, 8), 256, 0, stream>>>(Qh, Kh, S);
    softmax_ker<<<dim3(2048),      256, 0, stream>>>(S, linv);
    pv_gemm    <<<dim3(6, 16, 8),  256, 0, stream>>>(S, Vt, linv, out);
}

// Round 7
// 285.984 us; speedup vs baseline: 9.5582x; 1.6550x over previous
//
#include <hip/hip_runtime.h>
#include <math.h>

#define MM 16384
#define TT 2048
#define BB 8
#define CC 768
#define SOFT_SCALE 0.03608439182435161f   // 1/sqrt(768)

typedef _Float16 f16;
typedef _Float16 half8 __attribute__((ext_vector_type(8)));
typedef _Float16 half4 __attribute__((ext_vector_type(4)));
typedef float f32x4 __attribute__((ext_vector_type(4)));

// Swizzled LDS tile addressing: [128 rows][64 f16], row pitch 128 B.
// XOR byte bits 4-6 with row&7 -> conflict-free ds_read_b128 (T2).
__device__ __forceinline__ int swz(int r, int cbyte) {
    return r * 128 + (cbyte ^ ((r & 7) << 4));
}

// ---------------------------------------------------------------------------
// Kernel 0a: X fp32 -> f16 (exact-fit grid, no bounds check: 12582912/8/256=6144)
// ---------------------------------------------------------------------------
__global__ __launch_bounds__(256) void conv_x(const float* __restrict__ in,
                                              f16* __restrict__ out)
{
    const size_t i = ((size_t)blockIdx.x * 256 + threadIdx.x) * 8;
    float4 a = *(const float4*)(in + i);
    float4 b = *(const float4*)(in + i + 4);
    half8 h;
    h[0]=(f16)a.x; h[1]=(f16)a.y; h[2]=(f16)a.z; h[3]=(f16)a.w;
    h[4]=(f16)b.x; h[5]=(f16)b.y; h[6]=(f16)b.z; h[7]=(f16)b.w;
    *(half8*)(out + i) = h;
}

// Kernel 0b: W{q,k,v} fp32 -> concatenated f16 [3][768][768] (589824/8/256=288)
__global__ __launch_bounds__(256) void conv_w(const float* __restrict__ W0,
                                              const float* __restrict__ W1,
                                              const float* __restrict__ W2,
                                              f16* __restrict__ out)
{
    const int z = blockIdx.y;
    const float* __restrict__ in = (z == 0) ? W0 : (z == 1) ? W1 : W2;
    const size_t i = ((size_t)blockIdx.x * 256 + threadIdx.x) * 8;
    float4 a = *(const float4*)(in + i);
    float4 b = *(const float4*)(in + i + 4);
    half8 h;
    h[0]=(f16)a.x; h[1]=(f16)a.y; h[2]=(f16)a.z; h[3]=(f16)a.w;
    h[4]=(f16)b.x; h[5]=(f16)b.y; h[6]=(f16)b.z; h[7]=(f16)b.w;
    *(half8*)(out + (size_t)z * CC * CC + i) = h;
}

// ---------------------------------------------------------------------------
// Kernel 1: QKV projection, f16 in/out.  Y[m,n] = sum_k Xh[m,k] * Wh[z][n,k].
// 1D grid 2304 = 8 XCD-chunks x (16 m-tiles x 18 (z,n)).  Each XCD owns a
// contiguous m-range; the 18 (z,n) blocks of one m-tile are consecutive ->
// X-tile + W working set stay in the 4 MB per-XCD L2 (T1).
// z=0 -> Q, z=1 -> K (row-major), z=2 -> V transposed per batch Vt[b][d][t].
// ---------------------------------------------------------------------------
__global__ __launch_bounds__(256) void qkv_gemm_f16(
    const f16* __restrict__ Xh, const f16* __restrict__ Wh,
    f16* __restrict__ Qh, f16* __restrict__ Kh, f16* __restrict__ Vt)
{
    __shared__ char SM[34 * 1024];
    f16* As = (f16*)SM;
    f16* Bs = (f16*)(SM + 16 * 1024);

    const int d = blockIdx.x;               // 0..2303
    const int xcd = d & 7, idx = d >> 3;    // idx 0..287
    const int mt = xcd * 16 + idx / 18;
    const int sub = idx % 18;
    const int z = sub / 6, nt = sub % 6;
    const int m0 = mt * 128, n0 = nt * 128;

    const int tid = threadIdx.x;
    const int lane = tid & 63;
    const int w = tid >> 6;
    const int wr = w >> 1, wc = w & 1;
    const int l15 = lane & 15, lk = lane >> 4;

    f32x4 acc[4][4];
#pragma unroll
    for (int i = 0; i < 4; ++i)
#pragma unroll
        for (int j = 0; j < 4; ++j) acc[i][j] = (f32x4){0.f, 0.f, 0.f, 0.f};

    const int srow = tid >> 1;
    const int scol = (tid & 1) * 32;

    const f16* ga = Xh + (size_t)(m0 + srow) * CC + scol;
    const f16* gb = Wh + (size_t)z * CC * CC + (size_t)(n0 + srow) * CC + scol;

    half8 ra[4], rb[4];
#pragma unroll
    for (int i = 0; i < 4; ++i) {
        ra[i] = *(const half8*)(ga + i * 8);
        rb[i] = *(const half8*)(gb + i * 8);
    }

    for (int k0 = 0; k0 < CC; k0 += 64) {
        __syncthreads();
#pragma unroll
        for (int c = 0; c < 4; ++c) {
            *(half8*)((char*)As + swz(srow, (scol + c * 8) * 2)) = ra[c];
            *(half8*)((char*)Bs + swz(srow, (scol + c * 8) * 2)) = rb[c];
        }
        __syncthreads();
        if (k0 + 64 < CC) {
#pragma unroll
            for (int i = 0; i < 4; ++i) {
                ra[i] = *(const half8*)(ga + (k0 + 64) + i * 8);
                rb[i] = *(const half8*)(gb + (k0 + 64) + i * 8);
            }
        }
#pragma unroll
        for (int kk = 0; kk < 2; ++kk) {
            half8 a[4], b[4];
#pragma unroll
            for (int i = 0; i < 4; ++i)
                a[i] = *(const half8*)((char*)As + swz(wr * 64 + i * 16 + l15, (kk * 32 + lk * 8) * 2));
#pragma unroll
            for (int j = 0; j < 4; ++j)
                b[j] = *(const half8*)((char*)Bs + swz(wc * 64 + j * 16 + l15, (kk * 32 + lk * 8) * 2));
#pragma unroll
            for (int i = 0; i < 4; ++i)
#pragma unroll
                for (int j = 0; j < 4; ++j)
                    acc[i][j] = __builtin_amdgcn_mfma_f32_16x16x32_f16(a[i], b[j], acc[i][j], 0, 0, 0);
        }
    }

    if (z < 2) {
        f16* __restrict__ Y = (z == 0) ? Qh : Kh;
#pragma unroll
        for (int i = 0; i < 4; ++i)
#pragma unroll
            for (int r = 0; r < 4; ++r) {
                int m = m0 + wr * 64 + i * 16 + lk * 4 + r;
#pragma unroll
                for (int j = 0; j < 4; ++j) {
                    int n = n0 + wc * 64 + j * 16 + l15;
                    Y[(size_t)m * CC + n] = (f16)acc[i][j][r];
                }
            }
    } else {
        // transpose via LDS bounce: bounce[n][m], pitch 136 f16 (272 B -> every
        // row 16B-aligned so the half8 copy-out loads are legal ds_read_b128).
        __syncthreads();
        f16* Bn = (f16*)SM;
#pragma unroll
        for (int i = 0; i < 4; ++i)
#pragma unroll
            for (int j = 0; j < 4; ++j) {
                int n = wc * 64 + j * 16 + l15;
                int m = wr * 64 + i * 16 + lk * 4;
                half4 v;
#pragma unroll
                for (int r = 0; r < 4; ++r) v[r] = (f16)acc[i][j][r];
                *(half4*)&Bn[n * 136 + m] = v;
            }
        __syncthreads();
        const int b  = m0 >> 11;
        const int t0 = m0 & 2047;
        const int nrow = tid >> 1, mc = (tid & 1) * 64;
        f16* dst = Vt + (size_t)b * CC * TT + (size_t)(n0 + nrow) * TT + t0 + mc;
        const f16* src = &Bn[nrow * 136 + mc];
#pragma unroll
        for (int c = 0; c < 8; ++c) *(half8*)(dst + c * 8) = *(const half8*)(src + c * 8);
    }
}

// ---------------------------------------------------------------------------
// Kernel 2: S[b][t][s] = (Q[t,:] . K[s,:]) * scale, causal tiles only.
// 1D grid 1088 = 8 batches x 136 lower-triangular tiles; b = d&7 so each XCD
// keeps one batch's K panel L2-resident.
// ---------------------------------------------------------------------------
__global__ __launch_bounds__(256) void qk_gemm(
    const f16* __restrict__ Qh, const f16* __restrict__ Kh, f16* __restrict__ S)
{
    const int d = blockIdx.x;
    const int b = d & 7;
    const int tidx = d >> 3;                 // 0..135
    int ti = (int)((sqrtf(8.f * tidx + 1.f) - 1.f) * 0.5f);
    while ((ti + 1) * (ti + 2) / 2 <= tidx) ++ti;
    while (ti * (ti + 1) / 2 > tidx) --ti;
    const int tj = tidx - ti * (ti + 1) / 2;

    __shared__ char SM[32 * 1024];
    f16* As = (f16*)SM;
    f16* Bs = (f16*)(SM + 16 * 1024);

    const int tid = threadIdx.x;
    const int m0 = ti * 128, n0 = tj * 128;
    const int lane = tid & 63;
    const int w = tid >> 6;
    const int wr = w >> 1, wc = w & 1;
    const int l15 = lane & 15, lk = lane >> 4;

    f32x4 acc[4][4];
#pragma unroll
    for (int i = 0; i < 4; ++i)
#pragma unroll
        for (int j = 0; j < 4; ++j) acc[i][j] = (f32x4){0.f, 0.f, 0.f, 0.f};

    const int srow = tid >> 1;
    const int scol = (tid & 1) * 32;

    const f16* ga = Qh + (size_t)b * TT * CC + (size_t)(m0 + srow) * CC + scol;
    const f16* gb = Kh + (size_t)b * TT * CC + (size_t)(n0 + srow) * CC + scol;

    half8 ra[4], rb[4];
#pragma unroll
    for (int i = 0; i < 4; ++i) {
        ra[i] = *(const half8*)(ga + i * 8);
        rb[i] = *(const half8*)(gb + i * 8);
    }

    for (int k0 = 0; k0 < CC; k0 += 64) {
        __syncthreads();
#pragma unroll
        for (int c = 0; c < 4; ++c) {
            *(half8*)((char*)As + swz(srow, (scol + c * 8) * 2)) = ra[c];
            *(half8*)((char*)Bs + swz(srow, (scol + c * 8) * 2)) = rb[c];
        }
        __syncthreads();
        if (k0 + 64 < CC) {
#pragma unroll
            for (int i = 0; i < 4; ++i) {
                ra[i] = *(const half8*)(ga + (k0 + 64) + i * 8);
                rb[i] = *(const half8*)(gb + (k0 + 64) + i * 8);
            }
        }
#pragma unroll
        for (int kk = 0; kk < 2; ++kk) {
            half8 a[4], bfr[4];
#pragma unroll
            for (int i = 0; i < 4; ++i)
                a[i] = *(const half8*)((char*)As + swz(wr * 64 + i * 16 + l15, (kk * 32 + lk * 8) * 2));
#pragma unroll
            for (int j = 0; j < 4; ++j)
                bfr[j] = *(const half8*)((char*)Bs + swz(wc * 64 + j * 16 + l15, (kk * 32 + lk * 8) * 2));
#pragma unroll
            for (int i = 0; i < 4; ++i)
#pragma unroll
                for (int j = 0; j < 4; ++j)
                    acc[i][j] = __builtin_amdgcn_mfma_f32_16x16x32_f16(a[i], bfr[j], acc[i][j], 0, 0, 0);
        }
    }

    f16* Sb = S + (size_t)b * TT * TT;
#pragma unroll
    for (int i = 0; i < 4; ++i)
#pragma unroll
        for (int r = 0; r < 4; ++r) {
            int t = m0 + wr * 64 + i * 16 + lk * 4 + r;
#pragma unroll
            for (int j = 0; j < 4; ++j) {
                int s = n0 + wc * 64 + j * 16 + l15;
                Sb[(size_t)t * TT + s] = (f16)(acc[i][j][r] * SOFT_SCALE);
            }
        }
}

// ---------------------------------------------------------------------------
// Kernel 3: row softmax, in place (S -> P = exp(s-m)), stores 1/l.
// Wave per row; rows paired (t, 2047-t) for load balance. Zero-pads each row
// to its 128-tile boundary so pv_gemm never reads poison.
// ---------------------------------------------------------------------------
__global__ __launch_bounds__(256) void softmax_ker(
    f16* __restrict__ S, float* __restrict__ linv)
{
    const int w = threadIdx.x >> 6, lane = threadIdx.x & 63;
    const int pidx = blockIdx.x * 4 + w;       // 0..8191
    const int b = pidx >> 10, q = pidx & 1023;
    f16* Sb = S + (size_t)b * TT * TT;

#pragma unroll
    for (int hh = 0; hh < 2; ++hh) {
        const int t = hh ? (TT - 1 - q) : q;
        f16* row = Sb + (size_t)t * TT;
        const int L = t + 1;

        float m = -1e30f;
        for (int s = lane * 8; s < L; s += 512) {
            half8 v = *(const half8*)(row + s);
#pragma unroll
            for (int j = 0; j < 8; ++j) {
                float f = (float)v[j];
                m = (s + j < L) ? fmaxf(m, f) : m;
            }
        }
#pragma unroll
        for (int o = 32; o >= 1; o >>= 1) m = fmaxf(m, __shfl_xor(m, o));

        float sum = 0.f;
        for (int s = lane * 8; s < L; s += 512) {
            half8 v = *(const half8*)(row + s);
            half8 p;
#pragma unroll
            for (int j = 0; j < 8; ++j) {
                float e = (s + j < L) ? __expf((float)v[j] - m) : 0.f;
                sum += e;
                p[j] = (f16)e;
            }
            *(half8*)(row + s) = p;
        }
#pragma unroll
        for (int o = 32; o >= 1; o >>= 1) sum += __shfl_xor(sum, o);
        if (lane == 0) linv[b * TT + t] = 1.0f / sum;

        const int pe = ((t >> 7) + 1) << 7;     // pad to tile boundary
        for (int s = L + lane; s < pe; s += 64) row[s] = (f16)0.f;
    }
}

// ---------------------------------------------------------------------------
// Kernel 4: O[b][t][d] = (1/l) * sum_s P[t][s] * Vt[d][s], causal K-extent.
// 1D grid 768 = 8 batches x (16 ti x 6 dj), longest ti first; b = d&7.
// ---------------------------------------------------------------------------
__global__ __launch_bounds__(256) void pv_gemm(
    const f16* __restrict__ P, const f16* __restrict__ Vt,
    const float* __restrict__ linv, float* __restrict__ O)
{
    const int d = blockIdx.x;
    const int b = d & 7;
    const int r_ = d >> 3;                  // 0..95
    const int ti = 15 - r_ / 6;
    const int dj = r_ % 6;

    __shared__ char SM[32 * 1024];
    f16* As = (f16*)SM;
    f16* Bs = (f16*)(SM + 16 * 1024);

    const int tid = threadIdx.x;
    const int m0 = ti * 128, n0 = dj * 128;
    const int lane = tid & 63;
    const int w = tid >> 6;
    const int wr = w >> 1, wc = w & 1;
    const int l15 = lane & 15, lk = lane >> 4;

    f32x4 acc[4][4];
#pragma unroll
    for (int i = 0; i < 4; ++i)
#pragma unroll
        for (int j = 0; j < 4; ++j) acc[i][j] = (f32x4){0.f, 0.f, 0.f, 0.f};

    const int srow = tid >> 1;
    const int scol = (tid & 1) * 32;
    const int KE = (ti + 1) * 128;

    const f16* ga = P  + (size_t)b * TT * TT + (size_t)(m0 + srow) * TT + scol;
    const f16* gb = Vt + (size_t)b * CC * TT + (size_t)(n0 + srow) * TT + scol;

    half8 ra[4], rb[4];
#pragma unroll
    for (int i = 0; i < 4; ++i) {
        ra[i] = *(const half8*)(ga + i * 8);
        rb[i] = *(const half8*)(gb + i * 8);
    }

    for (int k0 = 0; k0 < KE; k0 += 64) {
        __syncthreads();
#pragma unroll
        for (int c = 0; c < 4; ++c) {
            *(half8*)((char*)As + swz(srow, (scol + c * 8) * 2)) = ra[c];
            *(half8*)((char*)Bs + swz(srow, (scol + c * 8) * 2)) = rb[c];
        }
        __syncthreads();
        if (k0 + 64 < KE) {
#pragma unroll
            for (int i = 0; i < 4; ++i) {
                ra[i] = *(const half8*)(ga + (k0 + 64) + i * 8);
                rb[i] = *(const half8*)(gb + (k0 + 64) + i * 8);
            }
        }
#pragma unroll
        for (int kk = 0; kk < 2; ++kk) {
            half8 a[4], bfr[4];
#pragma unroll
            for (int i = 0; i < 4; ++i)
                a[i] = *(const half8*)((char*)As + swz(wr * 64 + i * 16 + l15, (kk * 32 + lk * 8) * 2));
#pragma unroll
            for (int j = 0; j < 4; ++j)
                bfr[j] = *(const half8*)((char*)Bs + swz(wc * 64 + j * 16 + l15, (kk * 32 + lk * 8) * 2));
#pragma unroll
            for (int i = 0; i < 4; ++i)
#pragma unroll
                for (int j = 0; j < 4; ++j)
                    acc[i][j] = __builtin_amdgcn_mfma_f32_16x16x32_f16(a[i], bfr[j], acc[i][j], 0, 0, 0);
        }
    }

    float* Ob = O + (size_t)b * TT * CC;
#pragma unroll
    for (int i = 0; i < 4; ++i)
#pragma unroll
        for (int r = 0; r < 4; ++r) {
            int t = m0 + wr * 64 + i * 16 + lk * 4 + r;
            float sc = linv[b * TT + t];
#pragma unroll
            for (int j = 0; j < 4; ++j) {
                int dd = n0 + wc * 64 + j * 16 + l15;
                Ob[(size_t)t * CC + dd] = acc[i][j][r] * sc;
            }
        }
}

// ---------------------------------------------------------------------------
extern "C" void kernel_launch(void* const* d_in, const int* in_sizes, int n_in,
                              void* d_out, int out_size, void* d_ws, size_t ws_size,
                              hipStream_t stream) {
    (void)in_sizes; (void)n_in; (void)out_size; (void)ws_size;
    const float* x  = (const float*)d_in[0];
    const float* Wq = (const float*)d_in[1];
    const float* Wk = (const float*)d_in[2];
    const float* Wv = (const float*)d_in[3];

    f16* Qh = (f16*)d_ws;                             // 25.2 MB
    f16* Kh = Qh + (size_t)MM * CC;                   // 25.2 MB
    f16* Vt = Kh + (size_t)MM * CC;                   // 25.2 MB (transposed V)
    f16* S  = Vt + (size_t)MM * CC;                   // 67 MB  (S, then P in place)
    float* linv = (float*)(S + (size_t)BB * TT * TT); // 64 KB
    // Xh/Wh alias the S region: dead before qk_gemm writes S.
    f16* Xh = S;                                      // 25.2 MB
    f16* Wh = S + (size_t)MM * CC;                    // 3.5 MB
    float* out = (float*)d_out;

    conv_x      <<<6144, 256, 0, stream>>>(x, Xh);
    conv_w      <<<dim3(288, 3), 256, 0, stream>>>(Wq, Wk, Wv, Wh);
    qkv_gemm_f16<<<2304, 256, 0, stream>>>(Xh, Wh, Qh, Kh, Vt);
    qk_gemm     <<<1088, 256, 0, stream>>>(Qh, Kh, S);
    softmax_ker <<<2048, 256, 0, stream>>>(S, linv);
    pv_gemm     <<<768,  256, 0, stream>>>(S, Vt, linv, out);
}

// Round 10
// 278.703 us; speedup vs baseline: 9.8079x; 1.0261x over previous
//
#include <hip/hip_runtime.h>
#include <math.h>

#define MM 16384
#define TT 2048
#define BB 8
#define CC 768
#define SOFT_SCALE 0.03608439182435161f   // 1/sqrt(768)

typedef _Float16 f16;
typedef _Float16 half8 __attribute__((ext_vector_type(8)));
typedef _Float16 half4 __attribute__((ext_vector_type(4)));
typedef float f32x4 __attribute__((ext_vector_type(4)));

// Swizzled LDS tile addressing: [128 rows][64 f16], row pitch 128 B.
// XOR byte bits 4-6 with row&7 -> conflict-free ds_read_b128 (T2).
__device__ __forceinline__ int swz(int r, int cbyte) {
    return r * 128 + (cbyte ^ ((r & 7) << 4));
}

// Async global->LDS, 16 B per lane. LDS dest is wave-uniform base + lane*16
// (m104); global src is per-lane (m173) and carries the inverse swizzle so
// the swz() read side stays conflict-free (rule #21: both-sides-or-neither).
__device__ __forceinline__ void gload16(const void* g, void* l) {
    __builtin_amdgcn_global_load_lds(
        (const __attribute__((address_space(1))) void*)g,
        (__attribute__((address_space(3))) void*)l,
        16, 0, 0);
}

// ---------------------------------------------------------------------------
// Kernel 0a: X fp32 -> f16 (exact-fit grid: 12582912/8/256=6144)
// ---------------------------------------------------------------------------
__global__ __launch_bounds__(256) void conv_x(const float* __restrict__ in,
                                              f16* __restrict__ out)
{
    const size_t i = ((size_t)blockIdx.x * 256 + threadIdx.x) * 8;
    float4 a = *(const float4*)(in + i);
    float4 b = *(const float4*)(in + i + 4);
    half8 h;
    h[0]=(f16)a.x; h[1]=(f16)a.y; h[2]=(f16)a.z; h[3]=(f16)a.w;
    h[4]=(f16)b.x; h[5]=(f16)b.y; h[6]=(f16)b.z; h[7]=(f16)b.w;
    *(half8*)(out + i) = h;
}

// Kernel 0b: W{q,k,v} fp32 -> concatenated f16 [3][768][768] (589824/8/256=288)
__global__ __launch_bounds__(256) void conv_w(const float* __restrict__ W0,
                                              const float* __restrict__ W1,
                                              const float* __restrict__ W2,
                                              f16* __restrict__ out)
{
    const int z = blockIdx.y;
    const float* __restrict__ in = (z == 0) ? W0 : (z == 1) ? W1 : W2;
    const size_t i = ((size_t)blockIdx.x * 256 + threadIdx.x) * 8;
    float4 a = *(const float4*)(in + i);
    float4 b = *(const float4*)(in + i + 4);
    half8 h;
    h[0]=(f16)a.x; h[1]=(f16)a.y; h[2]=(f16)a.z; h[3]=(f16)a.w;
    h[4]=(f16)b.x; h[5]=(f16)b.y; h[6]=(f16)b.z; h[7]=(f16)b.w;
    *(half8*)(out + (size_t)z * CC * CC + i) = h;
}

// ---------------------------------------------------------------------------
// Kernel 1: QKV projection, f16 in/out.  Y[m,n] = sum_k Xh[m,k] * Wh[z][n,k].
// 1D grid 2304 = 8 XCD-chunks x (16 m-tiles x 18 (z,n)) for L2 locality (T1).
// Staging: global_load_lds w16, linear LDS + pre-swizzled source (m151/m173).
// z=0 -> Q, z=1 -> K (row-major), z=2 -> V transposed per batch Vt[b][d][t].
// ---------------------------------------------------------------------------
__global__ __launch_bounds__(256) void qkv_gemm_f16(
    const f16* __restrict__ Xh, const f16* __restrict__ Wh,
    f16* __restrict__ Qh, f16* __restrict__ Kh, f16* __restrict__ Vt)
{
    __shared__ char SM[34 * 1024];
    f16* As = (f16*)SM;
    f16* Bs = (f16*)(SM + 16 * 1024);

    const int d = blockIdx.x;               // 0..2303
    const int xcd = d & 7, idx = d >> 3;    // idx 0..287
    const int mt = xcd * 16 + idx / 18;
    const int sub = idx % 18;
    const int z = sub / 6, nt = sub % 6;
    const int m0 = mt * 128, n0 = nt * 128;

    const int tid = threadIdx.x;
    const int lane = tid & 63;
    const int w = tid >> 6;
    const int wr = w >> 1, wc = w & 1;
    const int l15 = lane & 15, lk = lane >> 4;

    f32x4 acc[4][4];
#pragma unroll
    for (int i = 0; i < 4; ++i)
#pragma unroll
        for (int j = 0; j < 4; ++j) acc[i][j] = (f32x4){0.f, 0.f, 0.f, 0.f};

    // staging geometry: wave w owns rows [w*32, w*32+32), chunk c = 8 rows.
    const int srow8 = lane >> 3;                   // 0..7 = row within chunk
    const int xcol  = ((lane & 7) ^ srow8) * 8;    // inverse-swizzled col (f16)

    const f16* ga = Xh + (size_t)(m0 + w * 32 + srow8) * CC + xcol;
    const f16* gb = Wh + (size_t)z * CC * CC + (size_t)(n0 + w * 32 + srow8) * CC + xcol;

    for (int k0 = 0; k0 < CC; k0 += 64) {
        __syncthreads();                            // previous tile consumed
#pragma unroll
        for (int c = 0; c < 4; ++c) {
            gload16(ga + (size_t)c * 8 * CC + k0, (char*)SM + (w * 4 + c) * 1024);
            gload16(gb + (size_t)c * 8 * CC + k0, (char*)SM + 16 * 1024 + (w * 4 + c) * 1024);
        }
        __syncthreads();                            // vmcnt drained before barrier
#pragma unroll
        for (int kk = 0; kk < 2; ++kk) {
            half8 a[4], b[4];
#pragma unroll
            for (int i = 0; i < 4; ++i)
                a[i] = *(const half8*)((char*)As + swz(wr * 64 + i * 16 + l15, (kk * 32 + lk * 8) * 2));
#pragma unroll
            for (int j = 0; j < 4; ++j)
                b[j] = *(const half8*)((char*)Bs + swz(wc * 64 + j * 16 + l15, (kk * 32 + lk * 8) * 2));
#pragma unroll
            for (int i = 0; i < 4; ++i)
#pragma unroll
                for (int j = 0; j < 4; ++j)
                    acc[i][j] = __builtin_amdgcn_mfma_f32_16x16x32_f16(a[i], b[j], acc[i][j], 0, 0, 0);
        }
    }

    if (z < 2) {
        f16* __restrict__ Y = (z == 0) ? Qh : Kh;
#pragma unroll
        for (int i = 0; i < 4; ++i)
#pragma unroll
            for (int r = 0; r < 4; ++r) {
                int m = m0 + wr * 64 + i * 16 + lk * 4 + r;
#pragma unroll
                for (int j = 0; j < 4; ++j) {
                    int n = n0 + wc * 64 + j * 16 + l15;
                    Y[(size_t)m * CC + n] = (f16)acc[i][j][r];
                }
            }
    } else {
        // transpose via LDS bounce: bounce[n][m], pitch 136 f16 (272 B -> every
        // row 16B-aligned so the half8 copy-out loads are legal ds_read_b128).
        __syncthreads();
        f16* Bn = (f16*)SM;
#pragma unroll
        for (int i = 0; i < 4; ++i)
#pragma unroll
            for (int j = 0; j < 4; ++j) {
                int n = wc * 64 + j * 16 + l15;
                int m = wr * 64 + i * 16 + lk * 4;
                half4 v;
#pragma unroll
                for (int r = 0; r < 4; ++r) v[r] = (f16)acc[i][j][r];
                *(half4*)&Bn[n * 136 + m] = v;
            }
        __syncthreads();
        const int b  = m0 >> 11;
        const int t0 = m0 & 2047;
        const int nrow = tid >> 1, mc = (tid & 1) * 64;
        f16* dst = Vt + (size_t)b * CC * TT + (size_t)(n0 + nrow) * TT + t0 + mc;
        const f16* src = &Bn[nrow * 136 + mc];
#pragma unroll
        for (int c = 0; c < 8; ++c) *(half8*)(dst + c * 8) = *(const half8*)(src + c * 8);
    }
}

// ---------------------------------------------------------------------------
// Kernel 2: S[b][t][s] = (Q[t,:] . K[s,:]) * scale, causal tiles only.
// 1D grid 1088 = 8 batches x 136 lower-triangular tiles; b = d&7 so each XCD
// keeps one batch's K panel L2-resident.
// ---------------------------------------------------------------------------
__global__ __launch_bounds__(256) void qk_gemm(
    const f16* __restrict__ Qh, const f16* __restrict__ Kh, f16* __restrict__ S)
{
    const int d = blockIdx.x;
    const int b = d & 7;
    const int tidx = d >> 3;                 // 0..135
    int ti = (int)((sqrtf(8.f * tidx + 1.f) - 1.f) * 0.5f);
    while ((ti + 1) * (ti + 2) / 2 <= tidx) ++ti;
    while (ti * (ti + 1) / 2 > tidx) --ti;
    const int tj = tidx - ti * (ti + 1) / 2;

    __shared__ char SM[32 * 1024];
    f16* As = (f16*)SM;
    f16* Bs = (f16*)(SM + 16 * 1024);

    const int tid = threadIdx.x;
    const int m0 = ti * 128, n0 = tj * 128;
    const int lane = tid & 63;
    const int w = tid >> 6;
    const int wr = w >> 1, wc = w & 1;
    const int l15 = lane & 15, lk = lane >> 4;

    f32x4 acc[4][4];
#pragma unroll
    for (int i = 0; i < 4; ++i)
#pragma unroll
        for (int j = 0; j < 4; ++j) acc[i][j] = (f32x4){0.f, 0.f, 0.f, 0.f};

    const int srow8 = lane >> 3;
    const int xcol  = ((lane & 7) ^ srow8) * 8;

    const f16* ga = Qh + (size_t)b * TT * CC + (size_t)(m0 + w * 32 + srow8) * CC + xcol;
    const f16* gb = Kh + (size_t)b * TT * CC + (size_t)(n0 + w * 32 + srow8) * CC + xcol;

    for (int k0 = 0; k0 < CC; k0 += 64) {
        __syncthreads();
#pragma unroll
        for (int c = 0; c < 4; ++c) {
            gload16(ga + (size_t)c * 8 * CC + k0, (char*)SM + (w * 4 + c) * 1024);
            gload16(gb + (size_t)c * 8 * CC + k0, (char*)SM + 16 * 1024 + (w * 4 + c) * 1024);
        }
        __syncthreads();
#pragma unroll
        for (int kk = 0; kk < 2; ++kk) {
            half8 a[4], bfr[4];
#pragma unroll
            for (int i = 0; i < 4; ++i)
                a[i] = *(const half8*)((char*)As + swz(wr * 64 + i * 16 + l15, (kk * 32 + lk * 8) * 2));
#pragma unroll
            for (int j = 0; j < 4; ++j)
                bfr[j] = *(const half8*)((char*)Bs + swz(wc * 64 + j * 16 + l15, (kk * 32 + lk * 8) * 2));
#pragma unroll
            for (int i = 0; i < 4; ++i)
#pragma unroll
                for (int j = 0; j < 4; ++j)
                    acc[i][j] = __builtin_amdgcn_mfma_f32_16x16x32_f16(a[i], bfr[j], acc[i][j], 0, 0, 0);
        }
    }

    f16* Sb = S + (size_t)b * TT * TT;
#pragma unroll
    for (int i = 0; i < 4; ++i)
#pragma unroll
        for (int r = 0; r < 4; ++r) {
            int t = m0 + wr * 64 + i * 16 + lk * 4 + r;
#pragma unroll
            for (int j = 0; j < 4; ++j) {
                int s = n0 + wc * 64 + j * 16 + l15;
                Sb[(size_t)t * TT + s] = (f16)(acc[i][j][r] * SOFT_SCALE);
            }
        }
}

// ---------------------------------------------------------------------------
// Kernel 3: row softmax, in place (S -> P = exp(s-m)), stores 1/l.
// Wave per row; rows paired (t, 2047-t) for load balance. Zero-pads each row
// to its 128-tile boundary so pv_gemm never reads poison.
// ---------------------------------------------------------------------------
__global__ __launch_bounds__(256) void softmax_ker(
    f16* __restrict__ S, float* __restrict__ linv)
{
    const int w = threadIdx.x >> 6, lane = threadIdx.x & 63;
    const int pidx = blockIdx.x * 4 + w;       // 0..8191
    const int b = pidx >> 10, q = pidx & 1023;
    f16* Sb = S + (size_t)b * TT * TT;

#pragma unroll
    for (int hh = 0; hh < 2; ++hh) {
        const int t = hh ? (TT - 1 - q) : q;
        f16* row = Sb + (size_t)t * TT;
        const int L = t + 1;

        float m = -1e30f;
        for (int s = lane * 8; s < L; s += 512) {
            half8 v = *(const half8*)(row + s);
#pragma unroll
            for (int j = 0; j < 8; ++j) {
                float f = (float)v[j];
                m = (s + j < L) ? fmaxf(m, f) : m;
            }
        }
#pragma unroll
        for (int o = 32; o >= 1; o >>= 1) m = fmaxf(m, __shfl_xor(m, o));

        float sum = 0.f;
        for (int s = lane * 8; s < L; s += 512) {
            half8 v = *(const half8*)(row + s);
            half8 p;
#pragma unroll
            for (int j = 0; j < 8; ++j) {
                float e = (s + j < L) ? __expf((float)v[j] - m) : 0.f;
                sum += e;
                p[j] = (f16)e;
            }
            *(half8*)(row + s) = p;
        }
#pragma unroll
        for (int o = 32; o >= 1; o >>= 1) sum += __shfl_xor(sum, o);
        if (lane == 0) linv[b * TT + t] = 1.0f / sum;

        const int pe = ((t >> 7) + 1) << 7;     // pad to tile boundary
        for (int s = L + lane; s < pe; s += 64) row[s] = (f16)0.f;
    }
}

// ---------------------------------------------------------------------------
// Kernel 4: O[b][t][d] = (1/l) * sum_s P[t][s] * Vt[d][s], causal K-extent.
// 1D grid 768 = 8 batches x (16 ti x 6 dj), longest ti first; b = d&7.
// ---------------------------------------------------------------------------
__global__ __launch_bounds__(256) void pv_gemm(
    const f16* __restrict__ P, const f16* __restrict__ Vt,
    const float* __restrict__ linv, float* __restrict__ O)
{
    const int d = blockIdx.x;
    const int b = d & 7;
    const int r_ = d >> 3;                  // 0..95
    const int ti = 15 - r_ / 6;
    const int dj = r_ % 6;

    __shared__ char SM[32 * 1024];
    f16* As = (f16*)SM;
    f16* Bs = (f16*)(SM + 16 * 1024);

    const int tid = threadIdx.x;
    const int m0 = ti * 128, n0 = dj * 128;
    const int lane = tid & 63;
    const int w = tid >> 6;
    const int wr = w >> 1, wc = w & 1;
    const int l15 = lane & 15, lk = lane >> 4;

    f32x4 acc[4][4];
#pragma unroll
    for (int i = 0; i < 4; ++i)
#pragma unroll
        for (int j = 0; j < 4; ++j) acc[i][j] = (f32x4){0.f, 0.f, 0.f, 0.f};

    const int srow8 = lane >> 3;
    const int xcol  = ((lane & 7) ^ srow8) * 8;
    const int KE = (ti + 1) * 128;

    const f16* ga = P  + (size_t)b * TT * TT + (size_t)(m0 + w * 32 + srow8) * TT + xcol;
    const f16* gb = Vt + (size_t)b * CC * TT + (size_t)(n0 + w * 32 + srow8) * TT + xcol;

    for (int k0 = 0; k0 < KE; k0 += 64) {
        __syncthreads();
#pragma unroll
        for (int c = 0; c < 4; ++c) {
            gload16(ga + (size_t)c * 8 * TT + k0, (char*)SM + (w * 4 + c) * 1024);
            gload16(gb + (size_t)c * 8 * TT + k0, (char*)SM + 16 * 1024 + (w * 4 + c) * 1024);
        }
        __syncthreads();
#pragma unroll
        for (int kk = 0; kk < 2; ++kk) {
            half8 a[4], bfr[4];
#pragma unroll
            for (int i = 0; i < 4; ++i)
                a[i] = *(const half8*)((char*)As + swz(wr * 64 + i * 16 + l15, (kk * 32 + lk * 8) * 2));
#pragma unroll
            for (int j = 0; j < 4; ++j)
                bfr[j] = *(const half8*)((char*)Bs + swz(wc * 64 + j * 16 + l15, (kk * 32 + lk * 8) * 2));
#pragma unroll
            for (int i = 0; i < 4; ++i)
#pragma unroll
                for (int j = 0; j < 4; ++j)
                    acc[i][j] = __builtin_amdgcn_mfma_f32_16x16x32_f16(a[i], bfr[j], acc[i][j], 0, 0, 0);
        }
    }

    float* Ob = O + (size_t)b * TT * CC;
#pragma unroll
    for (int i = 0; i < 4; ++i)
#pragma unroll
        for (int r = 0; r < 4; ++r) {
            int t = m0 + wr * 64 + i * 16 + lk * 4 + r;
            float sc = linv[b * TT + t];
#pragma unroll
            for (int j = 0; j < 4; ++j) {
                int dd = n0 + wc * 64 + j * 16 + l15;
                Ob[(size_t)t * CC + dd] = acc[i][j][r] * sc;
            }
        }
}

// ---------------------------------------------------------------------------
extern "C" void kernel_launch(void* const* d_in, const int* in_sizes, int n_in,
                              void* d_out, int out_size, void* d_ws, size_t ws_size,
                              hipStream_t stream) {
    (void)in_sizes; (void)n_in; (void)out_size; (void)ws_size;
    const float* x  = (const float*)d_in[0];
    const float* Wq = (const float*)d_in[1];
    const float* Wk = (const float*)d_in[2];
    const float* Wv = (const float*)d_in[3];

    f16* Qh = (f16*)d_ws;                             // 25.2 MB
    f16* Kh = Qh + (size_t)MM * CC;                   // 25.2 MB
    f16* Vt = Kh + (size_t)MM * CC;                   // 25.2 MB (transposed V)
    f16* S  = Vt + (size_t)MM * CC;                   // 67 MB  (S, then P in place)
    float* linv = (float*)(S + (size_t)BB * TT * TT); // 64 KB
    // Xh/Wh alias the S region: dead before qk_gemm writes S.
    f16* Xh = S;                                      // 25.2 MB
    f16* Wh = S + (size_t)MM * CC;                    // 3.5 MB
    float* out = (float*)d_out;

    conv_x      <<<6144, 256, 0, stream>>>(x, Xh);
    conv_w      <<<dim3(288, 3), 256, 0, stream>>>(Wq, Wk, Wv, Wh);
    qkv_gemm_f16<<<2304, 256, 0, stream>>>(Xh, Wh, Qh, Kh, Vt);
    qk_gemm     <<<1088, 256, 0, stream>>>(Qh, Kh, S);
    softmax_ker <<<2048, 256, 0, stream>>>(S, linv);
    pv_gemm     <<<768,  256, 0, stream>>>(S, Vt, linv, out);
}